// Round 14
// baseline (53.478 us; speedup 1.0000x reference)
//
#include <hip/hip_runtime.h>
#include <math.h>

#define NI   128
#define ND   32
#define NH   4
#define NNEI 120
#define KVW  640            // (ND+NI)*NH
#define NCOL 512            // NH*NI

// ---- DPP helpers: 16-lane reduction on the VALU pipe (no DS ops) ----
template<int CTRL>
__device__ __forceinline__ float dppf(float x) {
    return __int_as_float(__builtin_amdgcn_update_dpp(
        0, __float_as_int(x), CTRL, 0xF, 0xF, true));
}
__device__ __forceinline__ float red16_sum(float x) {
    x += dppf<0xB1>(x);
    x += dppf<0x4E>(x);
    x += dppf<0x141>(x);
    x += dppf<0x140>(x);
    return x;
}
__device__ __forceinline__ float red16_max(float x) {
    x = fmaxf(x, dppf<0xB1>(x));
    x = fmaxf(x, dppf<0x4E>(x));
    x = fmaxf(x, dppf<0x141>(x));
    x = fmaxf(x, dppf<0x140>(x));
    return x;
}

// ---------- legacy combined precompute (fallback path only) ----------
__global__ __launch_bounds__(256)
void precompute_MP(const float* __restrict__ Wq, const float* __restrict__ Wkv,
                   const float* __restrict__ Wh, float* __restrict__ M2, float* __restrict__ P2)
{
    int idx = blockIdx.x * 256 + threadIdx.x;
    if (idx < NI * NCOL) {
        int i  = idx & 127;
        int h  = (idx >> 7) & 3;
        int i2 = idx >> 9;
        float acc = 0.f;
        #pragma unroll 8
        for (int d = 0; d < ND; ++d)
            acc += Wq[i2 * NI + d * NH + h] * Wkv[i * KVW + d * NH + h];
        M2[i2 * NCOL + h * NI + i] = acc * 0.17677669529663687f;
    } else {
        int j  = idx - NI * NCOL;
        int io = j & 127;
        int i  = (j >> 7) & 127;
        int h  = j >> 14;
        float acc = 0.f;
        #pragma unroll 8
        for (int iv = 0; iv < NI; ++iv)
            acc += Wkv[i * KVW + (ND + iv) * NH + h] * Wh[(h * NI + iv) * NI + io];
        P2[j] = acc;
    }
}

// ---------- kernel 1: self-contained gemm1 (blocks 0..255) + P2 precompute (256..511) ----------
// gemm: qW[2048,512] = g1[2048,128] @ M2[128,512], where the block's M2 panel
// (128 x 64, single head h = n0/128) is computed IN-LDS from Wq/Wkv — no global
// M2 array, no separate precompute dispatch.
// P2[h*NI+i, io] = sum_iv Wkv[i,(ND+iv)*NH+h] * Wh[h*NI+iv, io]
#define G1_BM 64
#define G1_BN 64
#define G1_BK 32
__global__ __launch_bounds__(256)
void gemm1_p2(const float* __restrict__ g1, const float* __restrict__ Wq,
              const float* __restrict__ Wkv, const float* __restrict__ Wh,
              float* __restrict__ qW, float* __restrict__ P2)
{
    const int tid = threadIdx.x;

    if (blockIdx.x >= 256) {            // ---- P2 precompute part ----
        int j  = (blockIdx.x - 256) * 256 + tid;
        int io = j & 127;
        int i  = (j >> 7) & 127;
        int h  = j >> 14;
        float acc = 0.f;
        #pragma unroll 8
        for (int iv = 0; iv < NI; ++iv)
            acc += Wkv[i * KVW + (ND + iv) * NH + h] * Wh[(h * NI + iv) * NI + io];
        P2[j] = acc;
        return;
    }

    __shared__ float As[G1_BK][G1_BM + 4];
    __shared__ float Bs[G1_BK][G1_BN + 4];
    __shared__ float kw[G1_BN][ND + 1];      // k-weights for this block's 64 cols (8.4 KB)
    __shared__ float s_wq[G1_BK][ND + 1];    // Wq slice for current K-tile (4.2 KB)

    // ---- gemm part: C[M=2048, N=512] ----
    const int nbx = NCOL / G1_BN;                 // 8
    const int bx = blockIdx.x % nbx, by = blockIdx.x / nbx;
    const int m0 = by * G1_BM, n0 = bx * G1_BN;
    const int h  = bx >> 1;                       // head for this column band
    const int i0 = (bx & 1) * 64;                 // i-offset within head
    const int tx = tid & 15, ty = tid >> 4;
    const int N = NCOL, K = NI;

    // ---- stage kw[c][d] = Wkv[(i0+c)*KVW + d*NH + h] once ----
    #pragma unroll
    for (int e = 0; e < 8; ++e) {
        int u = tid + e * 256;
        int cc = u >> 5, d = u & 31;
        kw[cc][d] = Wkv[(size_t)(i0 + cc) * KVW + d * NH + h];
    }

    float acc[4][4] = {};
    for (int k0 = 0; k0 < K; k0 += G1_BK) {
        // A: 64x32 g1 tile, transposed into As
        #pragma unroll
        for (int e = 0; e < 2; ++e) {
            int uu = tid + e * 256;
            int rr = uu >> 3, c4 = uu & 7;
            float4 v = *(const float4*)(g1 + (size_t)(m0 + rr) * K + k0 + c4 * 4);
            As[c4 * 4 + 0][rr] = v.x;
            As[c4 * 4 + 1][rr] = v.y;
            As[c4 * 4 + 2][rr] = v.z;
            As[c4 * 4 + 3][rr] = v.w;
        }
        // Wq slice: s_wq[kk][d] = Wq[(k0+kk)*NI + d*NH + h]
        #pragma unroll
        for (int e = 0; e < 4; ++e) {
            int u = tid + e * 256;
            int kk = u >> 5, d = u & 31;
            s_wq[kk][d] = Wq[(size_t)(k0 + kk) * NI + d * NH + h];
        }
        __syncthreads();

        // Build Bs[kk][c] = scale * sum_d s_wq[kk][d] * kw[c][d]
        {
            const int kk = tid >> 3;              // 0..31
            const int c8 = (tid & 7) * 8;         // 8 consecutive cols
            float wrow[ND];
            #pragma unroll
            for (int d = 0; d < ND; ++d) wrow[d] = s_wq[kk][d];
            #pragma unroll
            for (int cc = 0; cc < 8; ++cc) {
                float a = 0.f;
                #pragma unroll
                for (int d = 0; d < ND; ++d) a += wrow[d] * kw[c8 + cc][d];
                Bs[kk][c8 + cc] = a * 0.17677669529663687f;
            }
        }
        __syncthreads();

        #pragma unroll
        for (int kk = 0; kk < G1_BK; ++kk) {
            float4 a4 = *(const float4*)&As[kk][ty * 4];
            float4 b4 = *(const float4*)&Bs[kk][tx * 4];
            float a[4] = {a4.x, a4.y, a4.z, a4.w};
            float b[4] = {b4.x, b4.y, b4.z, b4.w};
            #pragma unroll
            for (int m = 0; m < 4; ++m)
                #pragma unroll
                for (int n = 0; n < 4; ++n)
                    acc[m][n] += a[m] * b[n];
        }
        __syncthreads();
    }
    #pragma unroll
    for (int m = 0; m < 4; ++m) {
        int mm = m0 + ty * 4 + m;
        #pragma unroll
        for (int n = 0; n < 4; ++n)
            qW[(size_t)mm * N + n0 + tx * 4 + n] = acc[m][n];
    }
}

__device__ __forceinline__ bool load_mask(const void* p, int is_i32, int idx) {
    if (is_i32) return ((const int*)p)[idx] != 0;
    return ((const unsigned char*)p)[idx] != 0;
}

// ---- atten phase helpers (round-12/13 validated bodies) ----
__device__ __forceinline__ void load_rows(const float4* gbase, int w, int q, int c,
                                          float4 (&A)[8], float4 (&B)[8]) {
    #pragma unroll
    for (int t = 0; t < 8; ++t) {
        int j  = 16 * t + 4 * q + w;
        int jc = (j < NNEI) ? j : 0;
        A[t] = gbase[jc * 32 + c];
        B[t] = gbase[jc * 32 + c + 16];
    }
}

__device__ __forceinline__ void phase1_logits(
    const float4 (&rgA)[8], const float4 (&rgB)[8],
    const float4 (&qwA)[NH], const float4 (&qwB)[NH],
    float (*s_sm)[NNEI], int w, int q, int c)
{
    #pragma unroll
    for (int t = 0; t < 8; ++t) {
        float4 gA = rgA[t], gB = rgB[t];
        float s0, s1, s2, s3;
        s0 = qwA[0].x*gA.x + qwA[0].y*gA.y + qwA[0].z*gA.z + qwA[0].w*gA.w
           + qwB[0].x*gB.x + qwB[0].y*gB.y + qwB[0].z*gB.z + qwB[0].w*gB.w;
        s1 = qwA[1].x*gA.x + qwA[1].y*gA.y + qwA[1].z*gA.z + qwA[1].w*gA.w
           + qwB[1].x*gB.x + qwB[1].y*gB.y + qwB[1].z*gB.z + qwB[1].w*gB.w;
        s2 = qwA[2].x*gA.x + qwA[2].y*gA.y + qwA[2].z*gA.z + qwA[2].w*gA.w
           + qwB[2].x*gB.x + qwB[2].y*gB.y + qwB[2].z*gB.z + qwB[2].w*gB.w;
        s3 = qwA[3].x*gA.x + qwA[3].y*gA.y + qwA[3].z*gA.z + qwA[3].w*gA.w
           + qwB[3].x*gB.x + qwB[3].y*gB.y + qwB[3].z*gB.z + qwB[3].w*gB.w;
        s0 = red16_sum(s0);
        s1 = red16_sum(s1);
        s2 = red16_sum(s2);
        s3 = red16_sum(s3);
        int j = 16 * t + 4 * q + w;
        if (c == 0 && j < NNEI) {
            s_sm[0][j] = s0;
            s_sm[1][j] = s1;
            s_sm[2][j] = s2;
            s_sm[3][j] = s3;
        }
    }
}

__device__ __forceinline__ void softmax_inplace(
    float (*s_sm)[NNEI], int w, int lane,
    bool m0, bool m1, float sw0, float sw1)
{
    const int j0 = lane, j1 = lane + 64;
    const int j1c = (j1 < NNEI) ? j1 : 0;
    float v0 = m0 ? s_sm[w][j0] : -INFINITY;
    float v1 = m1 ? s_sm[w][j1c] : -INFINITY;

    float mx = fmaxf(v0, v1);
    mx = red16_max(mx);
    mx = fmaxf(mx, __shfl_xor(mx, 16));
    mx = fmaxf(mx, __shfl_xor(mx, 32));

    float e0 = 0.f, e1 = 0.f;
    if (mx != -INFINITY) {
        e0 = m0 ? __expf(v0 - mx) : 0.f;
        e1 = m1 ? __expf(v1 - mx) : 0.f;
    }
    float s = e0 + e1;
    s = red16_sum(s);
    s += __shfl_xor(s, 16);
    s += __shfl_xor(s, 32);
    float inv = (s > 0.f) ? (1.f / s) : 0.f;

    s_sm[w][j0] = e0 * inv * sw0;
    if (j1 < NNEI) s_sm[w][j1] = e1 * inv * sw1;
}

__device__ __forceinline__ void phase2_partial(
    const float4 (&rgA)[8], const float4 (&rgB)[8],
    float (*s_sm)[NNEI], float4 (*s_part2)[NH][33], int w, int q, int c)
{
    float4 aA[NH] = {}, aB[NH] = {};
    #pragma unroll
    for (int t = 0; t < 8; ++t) {
        int j = 16 * t + 4 * q + w;
        bool val = (j < NNEI);
        float4 gA = rgA[t], gB = rgB[t];
        #pragma unroll
        for (int h = 0; h < NH; ++h) {
            float a = val ? s_sm[h][j] : 0.f;
            aA[h].x += a * gA.x; aA[h].y += a * gA.y;
            aA[h].z += a * gA.z; aA[h].w += a * gA.w;
            aB[h].x += a * gB.x; aB[h].y += a * gB.y;
            aB[h].z += a * gB.z; aB[h].w += a * gB.w;
        }
    }
    #pragma unroll
    for (int h = 0; h < NH; ++h) {
        s_part2[w * 4 + q][h][c]      = aA[h];
        s_part2[w * 4 + q][h][c + 16] = aB[h];
    }
}

__device__ __forceinline__ void fold_t(
    const float4 (*s_part2)[NH][33], float4 (*s_t4a)[32], int tid)
{
    if (tid < 128) {
        int h = tid >> 5, cc = tid & 31;
        float4 r = {0.f, 0.f, 0.f, 0.f};
        #pragma unroll
        for (int g = 0; g < 16; ++g) {
            float4 v = s_part2[g][h][cc];
            r.x += v.x; r.y += v.y; r.z += v.z; r.w += v.w;
        }
        s_t4a[h][cc] = r;
    }
}

// ---------- kernel 2: 2 atoms/block sequential, shared P2 epilogue (round-13 validated) ----------
__global__ __launch_bounds__(256, 3)
void atten2_kernel(const float* __restrict__ gg1, const float* __restrict__ qW_all,
                   const void* __restrict__ mask_raw, const float* __restrict__ sw,
                   const float* __restrict__ P2, const float* __restrict__ bh,
                   float* __restrict__ out)
{
    __shared__ float  s_sm[NH][NNEI];        // logits -> attn in place
    __shared__ float4 s_part2[16][NH][33];   // 33.8 KB scratch (partial-t, P2 partials)
    __shared__ float4 s_t4[2][NH][32];       // 4 KB final t for both atoms
    __shared__ int    s_is_i32;

    const int tid  = threadIdx.x;
    const int bl0  = blockIdx.x * 2;
    const int bl1  = bl0 + 1;
    const int w    = tid >> 6;
    const int lane = tid & 63;
    const int q    = lane >> 4;
    const int c    = lane & 15;
    const int j0   = lane, j1 = lane + 64;
    const int j1c  = (j1 < NNEI) ? j1 : 0;

    if (tid < 64) {
        unsigned v = ((const unsigned*)mask_raw)[tid];
        unsigned long long b = __ballot(v <= 1u);
        if (tid == 0) s_is_i32 = (b == 0xFFFFFFFFFFFFFFFFull) ? 1 : 0;
    }

    // ---- atom0 hoisted mask/sw (both dtype interpretations; select later) ----
    float sw0_0 = sw[bl0 * NNEI + j0];
    float sw1_0 = (j1 < NNEI) ? sw[bl0 * NNEI + j1] : 0.f;
    unsigned a0mi0 = ((const int*)mask_raw)[bl0 * NNEI + j0];
    unsigned a0mi1 = ((const int*)mask_raw)[bl0 * NNEI + j1c];
    unsigned a0mb0 = ((const unsigned char*)mask_raw)[bl0 * NNEI + j0];
    unsigned a0mb1 = ((const unsigned char*)mask_raw)[bl0 * NNEI + j1c];

    // ---- atom0 gg rows + qW fragments ----
    const float4* gb0 = (const float4*)(gg1 + (size_t)bl0 * NNEI * NI);
    const float4* gb1 = (const float4*)(gg1 + (size_t)bl1 * NNEI * NI);
    float4 rgA[8], rgB[8];
    load_rows(gb0, w, q, c, rgA, rgB);

    const float4* qwb0 = (const float4*)(qW_all + (size_t)bl0 * NCOL);
    float4 qwA[NH], qwB[NH];
    #pragma unroll
    for (int h = 0; h < NH; ++h) {
        qwA[h] = qwb0[h * 32 + c];
        qwB[h] = qwb0[h * 32 + c + 16];
    }

    // ================= atom 0 =================
    phase1_logits(rgA, rgB, qwA, qwB, s_sm, w, q, c);
    __syncthreads();
    const int is32 = s_is_i32;
    {
        bool m0 = is32 ? (a0mi0 != 0u) : (a0mb0 != 0u);
        bool m1 = (j1 < NNEI) && (is32 ? (a0mi1 != 0u) : (a0mb1 != 0u));
        softmax_inplace(s_sm, w, lane, m0, m1, sw0_0, sw1_0);
    }
    __syncthreads();
    phase2_partial(rgA, rgB, s_sm, s_part2, w, q, c);

    // ---- early-issue atom1 state (rg regs free after phase2) ----
    load_rows(gb1, w, q, c, rgA, rgB);
    const float4* qwb1 = (const float4*)(qW_all + (size_t)bl1 * NCOL);
    #pragma unroll
    for (int h = 0; h < NH; ++h) {
        qwA[h] = qwb1[h * 32 + c];
        qwB[h] = qwb1[h * 32 + c + 16];
    }
    bool a1m0 = load_mask(mask_raw, is32, bl1 * NNEI + j0);
    bool a1m1 = (j1 < NNEI) && load_mask(mask_raw, is32, bl1 * NNEI + j1c);
    float sw0_1 = sw[bl1 * NNEI + j0];
    float sw1_1 = (j1 < NNEI) ? sw[bl1 * NNEI + j1] : 0.f;

    __syncthreads();
    fold_t(s_part2, s_t4[0], tid);
    __syncthreads();

    // ================= atom 1 =================
    phase1_logits(rgA, rgB, qwA, qwB, s_sm, w, q, c);
    __syncthreads();
    softmax_inplace(s_sm, w, lane, a1m0, a1m1, sw0_1, sw1_1);
    __syncthreads();
    phase2_partial(rgA, rgB, s_sm, s_part2, w, q, c);
    __syncthreads();
    fold_t(s_part2, s_t4[1], tid);
    __syncthreads();

    // ---- shared epilogue: out[a] = t[a] @ P2 + bh, P2 read once ----
    {
        const int io4 = tid & 31, g = tid >> 5;       // g in 0..7
        float4 o0 = {0.f, 0.f, 0.f, 0.f};
        float4 o1 = {0.f, 0.f, 0.f, 0.f};
        const float4* P2_4 = (const float4*)P2;       // [512][32] float4
        const float* t0f = (const float*)&s_t4[0][0][0];
        const float* t1f = (const float*)&s_t4[1][0][0];
        #pragma unroll 8
        for (int it = 0; it < 64; ++it) {
            int kk = it * 8 + g;
            float4 p = P2_4[kk * 32 + io4];
            float tv0 = t0f[kk];
            float tv1 = t1f[kk];
            o0.x += tv0 * p.x; o0.y += tv0 * p.y; o0.z += tv0 * p.z; o0.w += tv0 * p.w;
            o1.x += tv1 * p.x; o1.y += tv1 * p.y; o1.z += tv1 * p.z; o1.w += tv1 * p.w;
        }
        float4* s_pp = &s_part2[0][0][0];
        s_pp[g * 33 + io4]       = o0;
        s_pp[264 + g * 33 + io4] = o1;                 // 264 = 8*33
    }
    __syncthreads();
    if (tid < 64) {
        int a = tid >> 5, io4 = tid & 31;
        const float4* s_pp = &s_part2[0][0][0];
        float4 r = {0.f, 0.f, 0.f, 0.f};
        #pragma unroll
        for (int g = 0; g < 8; ++g) {
            float4 v = s_pp[a * 264 + g * 33 + io4];
            r.x += v.x; r.y += v.y; r.z += v.z; r.w += v.w;
        }
        float4 b = ((const float4*)bh)[io4];
        r.x += b.x; r.y += b.y; r.z += b.z; r.w += b.w;
        ((float4*)out)[(size_t)(bl0 + a) * 32 + io4] = r;
    }
}

// ---------- fallback: single fused kernel (round-2 structure, M2/P2 layouts) ----------
__global__ __launch_bounds__(256, 2)
void fused_fallback(const float* __restrict__ g1, const float* __restrict__ gg1,
                    const void* __restrict__ mask_raw, const float* __restrict__ sw,
                    const float* __restrict__ M2, const float* __restrict__ P2,
                    const float* __restrict__ bh, float* __restrict__ out)
{
    __shared__ float s_gg[NNEI * 129];
    __shared__ float s_qW[NH][NI];
    __shared__ float s_attn[NH][NNEI];
    __shared__ float s_t[NH][NI];
    __shared__ float s_part[2][NI];
    __shared__ int   s_is_i32;

    const int tid = threadIdx.x;
    const int bl  = blockIdx.x;

    if (tid < 64) {
        unsigned v = ((const unsigned*)mask_raw)[tid];
        unsigned long long b = __ballot(v <= 1u);
        if (tid == 0) s_is_i32 = (b == 0xFFFFFFFFFFFFFFFFull) ? 1 : 0;
    }
    {
        const float4* gsrc = (const float4*)(gg1 + (size_t)bl * NNEI * NI);
        #pragma unroll
        for (int p = 0; p < 15; ++p) {
            int u = tid + p * 256;
            int r = u >> 5, c4 = u & 31;
            float4 v = gsrc[u];
            float* dst = &s_gg[r * 129 + c4 * 4];
            dst[0] = v.x; dst[1] = v.y; dst[2] = v.z; dst[3] = v.w;
        }
    }
    {
        const float* g1r = g1 + bl * NI;
        #pragma unroll
        for (int p = 0; p < 2; ++p) {
            int o = tid + p * 256;
            int i = o & (NI - 1);
            int h = o >> 7;
            const float* Mp = M2 + h * NI + i;
            float acc = 0.f;
            #pragma unroll 8
            for (int i2 = 0; i2 < NI; ++i2) acc += g1r[i2] * Mp[i2 * NCOL];
            s_qW[h][i] = acc;
        }
    }
    __syncthreads();
    {
        const int lane = tid & 63, h = tid >> 6;
        const int j0 = lane, j1 = lane + 64;
        const int j1c = (j1 < NNEI) ? j1 : 0;
        const float* row0 = &s_gg[j0 * 129];
        const float* row1 = &s_gg[j1c * 129];
        float dot0 = 0.f, dot1 = 0.f;
        #pragma unroll 8
        for (int i = 0; i < NI; ++i) {
            float w = s_qW[h][i];
            dot0 += row0[i] * w;
            dot1 += row1[i] * w;
        }
        bool m0 = load_mask(mask_raw, s_is_i32, bl * NNEI + j0);
        bool m1 = (j1 < NNEI) && load_mask(mask_raw, s_is_i32, bl * NNEI + j1c);
        float v0 = m0 ? dot0 : -INFINITY;
        float v1 = m1 ? dot1 : -INFINITY;
        float mx = fmaxf(v0, v1);
        #pragma unroll
        for (int off = 32; off; off >>= 1) mx = fmaxf(mx, __shfl_xor(mx, off));
        float e0 = 0.f, e1 = 0.f;
        if (mx != -INFINITY) {
            e0 = m0 ? __expf(v0 - mx) : 0.f;
            e1 = m1 ? __expf(v1 - mx) : 0.f;
        }
        float s = e0 + e1;
        #pragma unroll
        for (int off = 32; off; off >>= 1) s += __shfl_xor(s, off);
        float inv = (s > 0.f) ? (1.f / s) : 0.f;
        s_attn[h][j0] = e0 * inv * sw[bl * NNEI + j0];
        if (j1 < NNEI) s_attn[h][j1] = e1 * inv * sw[bl * NNEI + j1];
    }
    __syncthreads();
    #pragma unroll
    for (int p = 0; p < 2; ++p) {
        int o = tid + p * 256;
        int i = o & (NI - 1);
        int h = o >> 7;
        float acc = 0.f;
        #pragma unroll 8
        for (int j = 0; j < NNEI; ++j) acc += s_attn[h][j] * s_gg[j * 129 + i];
        s_t[h][i] = acc;
    }
    __syncthreads();
    {
        int io = tid & (NI - 1);
        int half = tid >> 7;
        float acc = 0.f;
        #pragma unroll 2
        for (int h = half * 2; h < half * 2 + 2; ++h) {
            const float* Pp = P2 + h * NI * NI + io;
            #pragma unroll 8
            for (int i = 0; i < NI; ++i) acc += s_t[h][i] * Pp[i * NI];
        }
        s_part[half][io] = acc;
    }
    __syncthreads();
    if (tid < NI)
        out[bl * NI + tid] = s_part[0][tid] + s_part[1][tid] + bh[tid];
}

extern "C" void kernel_launch(void* const* d_in, const int* in_sizes, int n_in,
                              void* d_out, int out_size, void* d_ws, size_t ws_size,
                              hipStream_t stream) {
    const float* g1   = (const float*)d_in[0];
    const float* gg1  = (const float*)d_in[1];
    const void*  mask = d_in[2];
    const float* sw   = (const float*)d_in[3];
    const float* Wq   = (const float*)d_in[4];
    const float* Wkv  = (const float*)d_in[5];
    const float* Wh   = (const float*)d_in[6];
    const float* bh   = (const float*)d_in[7];
    float* out = (float*)d_out;

    const int nbl = in_sizes[0] / NI;                 // nb*nloc = 2048
    const size_t nM = (size_t)NI * NCOL;              // 65536
    const size_t nP = (size_t)NCOL * NI;              // 65536
    const size_t nQ = (size_t)nbl * NCOL;             // 1048576

    float* M2 = (float*)d_ws;
    float* P2 = M2 + nM;

    const bool main_path = (ws_size >= (nM + nP + nQ) * sizeof(float)) &&
                           (nbl == 2048);

    if (main_path) {
        float* qW = P2 + nP;
        gemm1_p2<<<512, 256, 0, stream>>>(g1, Wq, Wkv, Wh, qW, P2);
        atten2_kernel<<<nbl / 2, 256, 0, stream>>>(gg1, qW, mask, sw, P2, bh, out);
    } else {
        precompute_MP<<<512, 256, 0, stream>>>(Wq, Wkv, Wh, M2, P2);
        fused_fallback<<<nbl, 256, 0, stream>>>(g1, gg1, mask, sw, M2, P2, bh, out);
    }
}

// Round 15
// 51.856 us; speedup vs baseline: 1.0313x; 1.0313x over previous
//
#include <hip/hip_runtime.h>
#include <math.h>

#define NI   128
#define ND   32
#define NH   4
#define NNEI 120
#define KVW  640            // (ND+NI)*NH
#define NCOL 512            // NH*NI

// ---- DPP helpers: 16-lane reduction on the VALU pipe (no DS ops) ----
template<int CTRL>
__device__ __forceinline__ float dppf(float x) {
    return __int_as_float(__builtin_amdgcn_update_dpp(
        0, __float_as_int(x), CTRL, 0xF, 0xF, true));
}
__device__ __forceinline__ float red16_sum(float x) {
    x += dppf<0xB1>(x);
    x += dppf<0x4E>(x);
    x += dppf<0x141>(x);
    x += dppf<0x140>(x);
    return x;
}
__device__ __forceinline__ float red16_max(float x) {
    x = fmaxf(x, dppf<0xB1>(x));
    x = fmaxf(x, dppf<0x4E>(x));
    x = fmaxf(x, dppf<0x141>(x));
    x = fmaxf(x, dppf<0x140>(x));
    return x;
}

// ---------- kernel 1a: M2 only (256 blocks) ----------
// M2[i2, h*NI+i] = (1/sqrt(ND)) * sum_d Wq[i2, d*NH+h] * Wkv[i, d*NH+h]
__global__ __launch_bounds__(256)
void precompute_M2(const float* __restrict__ Wq, const float* __restrict__ Wkv,
                   float* __restrict__ M2)
{
    int idx = blockIdx.x * 256 + threadIdx.x;
    int i  = idx & 127;
    int h  = (idx >> 7) & 3;
    int i2 = idx >> 9;
    float acc = 0.f;
    #pragma unroll 8
    for (int d = 0; d < ND; ++d)
        acc += Wq[i2 * NI + d * NH + h] * Wkv[i * KVW + d * NH + h];
    M2[i2 * NCOL + h * NI + i] = acc * 0.17677669529663687f;
}

// ---------- legacy combined precompute (fallback path only) ----------
__global__ __launch_bounds__(256)
void precompute_MP(const float* __restrict__ Wq, const float* __restrict__ Wkv,
                   const float* __restrict__ Wh, float* __restrict__ M2, float* __restrict__ P2)
{
    int idx = blockIdx.x * 256 + threadIdx.x;
    if (idx < NI * NCOL) {
        int i  = idx & 127;
        int h  = (idx >> 7) & 3;
        int i2 = idx >> 9;
        float acc = 0.f;
        #pragma unroll 8
        for (int d = 0; d < ND; ++d)
            acc += Wq[i2 * NI + d * NH + h] * Wkv[i * KVW + d * NH + h];
        M2[i2 * NCOL + h * NI + i] = acc * 0.17677669529663687f;
    } else {
        int j  = idx - NI * NCOL;
        int io = j & 127;
        int i  = (j >> 7) & 127;
        int h  = j >> 14;
        float acc = 0.f;
        #pragma unroll 8
        for (int iv = 0; iv < NI; ++iv)
            acc += Wkv[i * KVW + (ND + iv) * NH + h] * Wh[(h * NI + iv) * NI + io];
        P2[j] = acc;
    }
}

// ---------- kernel 2: gemm1 (blocks 0..255) grid-fused with P2 precompute (256..511) ----------
// gemm: qW[2048,512] = g1[2048,128] @ M2[128,512]   (BM=64,BN=64,BK=32,TM=4,TN=4)
// P2[h*NI+i, io] = sum_iv Wkv[i,(ND+iv)*NH+h] * Wh[h*NI+iv, io]
#define G1_BM 64
#define G1_BN 64
#define G1_BK 32
__global__ __launch_bounds__(256)
void gemm1_p2(const float* __restrict__ g1, const float* __restrict__ M2,
              const float* __restrict__ Wkv, const float* __restrict__ Wh,
              float* __restrict__ qW, float* __restrict__ P2)
{
    __shared__ float As[G1_BK][G1_BM + 4];
    __shared__ float Bs[G1_BK][G1_BN + 4];
    const int tid = threadIdx.x;

    if (blockIdx.x >= 256) {            // ---- P2 precompute part ----
        int j  = (blockIdx.x - 256) * 256 + tid;
        int io = j & 127;
        int i  = (j >> 7) & 127;
        int h  = j >> 14;
        float acc = 0.f;
        #pragma unroll 8
        for (int iv = 0; iv < NI; ++iv)
            acc += Wkv[i * KVW + (ND + iv) * NH + h] * Wh[(h * NI + iv) * NI + io];
        P2[j] = acc;
        return;
    }

    // ---- gemm part: C[M=2048, N=512] ----
    const int nbx = NCOL / G1_BN;                 // 8
    const int bx = blockIdx.x % nbx, by = blockIdx.x / nbx;
    const int m0 = by * G1_BM, n0 = bx * G1_BN;
    const int tx = tid & 15, ty = tid >> 4;
    const int N = NCOL, K = NI;

    float acc[4][4] = {};
    for (int k0 = 0; k0 < K; k0 += G1_BK) {
        {   // A: 64x32 tile, transposed into As
            #pragma unroll
            for (int e = 0; e < 2; ++e) {
                int uu = tid + e * 256;
                int rr = uu >> 3, c4 = uu & 7;
                float4 v = *(const float4*)(g1 + (size_t)(m0 + rr) * K + k0 + c4 * 4);
                As[c4 * 4 + 0][rr] = v.x;
                As[c4 * 4 + 1][rr] = v.y;
                As[c4 * 4 + 2][rr] = v.z;
                As[c4 * 4 + 3][rr] = v.w;
            }
        }
        {   // B: 32x64 tile
            #pragma unroll
            for (int e = 0; e < 2; ++e) {
                int uu = tid + e * 256;
                int kk = uu >> 4, c4 = uu & 15;
                float4 v = *(const float4*)(M2 + (size_t)(k0 + kk) * N + n0 + c4 * 4);
                *(float4*)&Bs[kk][c4 * 4] = v;
            }
        }
        __syncthreads();
        #pragma unroll
        for (int kk = 0; kk < G1_BK; ++kk) {
            float4 a4 = *(const float4*)&As[kk][ty * 4];
            float4 b4 = *(const float4*)&Bs[kk][tx * 4];
            float a[4] = {a4.x, a4.y, a4.z, a4.w};
            float b[4] = {b4.x, b4.y, b4.z, b4.w};
            #pragma unroll
            for (int m = 0; m < 4; ++m)
                #pragma unroll
                for (int n = 0; n < 4; ++n)
                    acc[m][n] += a[m] * b[n];
        }
        __syncthreads();
    }
    #pragma unroll
    for (int m = 0; m < 4; ++m) {
        int mm = m0 + ty * 4 + m;
        #pragma unroll
        for (int n = 0; n < 4; ++n)
            qW[(size_t)mm * N + n0 + tx * 4 + n] = acc[m][n];
    }
}

__device__ __forceinline__ bool load_mask(const void* p, int is_i32, int idx) {
    if (is_i32) return ((const int*)p)[idx] != 0;
    return ((const unsigned char*)p)[idx] != 0;
}

// ---- atten phase helpers (round-12/13 validated bodies) ----
__device__ __forceinline__ void load_rows(const float4* gbase, int w, int q, int c,
                                          float4 (&A)[8], float4 (&B)[8]) {
    #pragma unroll
    for (int t = 0; t < 8; ++t) {
        int j  = 16 * t + 4 * q + w;
        int jc = (j < NNEI) ? j : 0;
        A[t] = gbase[jc * 32 + c];
        B[t] = gbase[jc * 32 + c + 16];
    }
}

__device__ __forceinline__ void phase1_logits(
    const float4 (&rgA)[8], const float4 (&rgB)[8],
    const float4 (&qwA)[NH], const float4 (&qwB)[NH],
    float (*s_sm)[NNEI], int w, int q, int c)
{
    #pragma unroll
    for (int t = 0; t < 8; ++t) {
        float4 gA = rgA[t], gB = rgB[t];
        float s0, s1, s2, s3;
        s0 = qwA[0].x*gA.x + qwA[0].y*gA.y + qwA[0].z*gA.z + qwA[0].w*gA.w
           + qwB[0].x*gB.x + qwB[0].y*gB.y + qwB[0].z*gB.z + qwB[0].w*gB.w;
        s1 = qwA[1].x*gA.x + qwA[1].y*gA.y + qwA[1].z*gA.z + qwA[1].w*gA.w
           + qwB[1].x*gB.x + qwB[1].y*gB.y + qwB[1].z*gB.z + qwB[1].w*gB.w;
        s2 = qwA[2].x*gA.x + qwA[2].y*gA.y + qwA[2].z*gA.z + qwA[2].w*gA.w
           + qwB[2].x*gB.x + qwB[2].y*gB.y + qwB[2].z*gB.z + qwB[2].w*gB.w;
        s3 = qwA[3].x*gA.x + qwA[3].y*gA.y + qwA[3].z*gA.z + qwA[3].w*gA.w
           + qwB[3].x*gB.x + qwB[3].y*gB.y + qwB[3].z*gB.z + qwB[3].w*gB.w;
        s0 = red16_sum(s0);
        s1 = red16_sum(s1);
        s2 = red16_sum(s2);
        s3 = red16_sum(s3);
        int j = 16 * t + 4 * q + w;
        if (c == 0 && j < NNEI) {
            s_sm[0][j] = s0;
            s_sm[1][j] = s1;
            s_sm[2][j] = s2;
            s_sm[3][j] = s3;
        }
    }
}

__device__ __forceinline__ void softmax_inplace(
    float (*s_sm)[NNEI], int w, int lane,
    bool m0, bool m1, float sw0, float sw1)
{
    const int j0 = lane, j1 = lane + 64;
    const int j1c = (j1 < NNEI) ? j1 : 0;
    float v0 = m0 ? s_sm[w][j0] : -INFINITY;
    float v1 = m1 ? s_sm[w][j1c] : -INFINITY;

    float mx = fmaxf(v0, v1);
    mx = red16_max(mx);
    mx = fmaxf(mx, __shfl_xor(mx, 16));
    mx = fmaxf(mx, __shfl_xor(mx, 32));

    float e0 = 0.f, e1 = 0.f;
    if (mx != -INFINITY) {
        e0 = m0 ? __expf(v0 - mx) : 0.f;
        e1 = m1 ? __expf(v1 - mx) : 0.f;
    }
    float s = e0 + e1;
    s = red16_sum(s);
    s += __shfl_xor(s, 16);
    s += __shfl_xor(s, 32);
    float inv = (s > 0.f) ? (1.f / s) : 0.f;

    s_sm[w][j0] = e0 * inv * sw0;
    if (j1 < NNEI) s_sm[w][j1] = e1 * inv * sw1;
}

__device__ __forceinline__ void phase2_partial(
    const float4 (&rgA)[8], const float4 (&rgB)[8],
    float (*s_sm)[NNEI], float4 (*s_part2)[NH][33], int w, int q, int c)
{
    float4 aA[NH] = {}, aB[NH] = {};
    #pragma unroll
    for (int t = 0; t < 8; ++t) {
        int j = 16 * t + 4 * q + w;
        bool val = (j < NNEI);
        float4 gA = rgA[t], gB = rgB[t];
        #pragma unroll
        for (int h = 0; h < NH; ++h) {
            float a = val ? s_sm[h][j] : 0.f;
            aA[h].x += a * gA.x; aA[h].y += a * gA.y;
            aA[h].z += a * gA.z; aA[h].w += a * gA.w;
            aB[h].x += a * gB.x; aB[h].y += a * gB.y;
            aB[h].z += a * gB.z; aB[h].w += a * gB.w;
        }
    }
    #pragma unroll
    for (int h = 0; h < NH; ++h) {
        s_part2[w * 4 + q][h][c]      = aA[h];
        s_part2[w * 4 + q][h][c + 16] = aB[h];
    }
}

__device__ __forceinline__ void fold_t(
    const float4 (*s_part2)[NH][33], float4 (*s_t4a)[32], int tid)
{
    if (tid < 128) {
        int h = tid >> 5, cc = tid & 31;
        float4 r = {0.f, 0.f, 0.f, 0.f};
        #pragma unroll
        for (int g = 0; g < 16; ++g) {
            float4 v = s_part2[g][h][cc];
            r.x += v.x; r.y += v.y; r.z += v.z; r.w += v.w;
        }
        s_t4a[h][cc] = r;
    }
}

// ---------- kernel 3: 2 atoms/block sequential, shared P2 epilogue ----------
__global__ __launch_bounds__(256, 3)
void atten2_kernel(const float* __restrict__ gg1, const float* __restrict__ qW_all,
                   const void* __restrict__ mask_raw, const float* __restrict__ sw,
                   const float* __restrict__ P2, const float* __restrict__ bh,
                   float* __restrict__ out)
{
    __shared__ float  s_sm[NH][NNEI];        // logits -> attn in place
    __shared__ float4 s_part2[16][NH][33];   // 33.8 KB scratch (partial-t, P2 partials)
    __shared__ float4 s_t4[2][NH][32];       // 4 KB final t for both atoms
    __shared__ int    s_is_i32;

    const int tid  = threadIdx.x;
    const int bl0  = blockIdx.x * 2;
    const int bl1  = bl0 + 1;
    const int w    = tid >> 6;
    const int lane = tid & 63;
    const int q    = lane >> 4;
    const int c    = lane & 15;
    const int j0   = lane, j1 = lane + 64;
    const int j1c  = (j1 < NNEI) ? j1 : 0;

    if (tid < 64) {
        unsigned v = ((const unsigned*)mask_raw)[tid];
        unsigned long long b = __ballot(v <= 1u);
        if (tid == 0) s_is_i32 = (b == 0xFFFFFFFFFFFFFFFFull) ? 1 : 0;
    }

    // ---- atom0 hoisted mask/sw (both dtype interpretations; select later) ----
    float sw0_0 = sw[bl0 * NNEI + j0];
    float sw1_0 = (j1 < NNEI) ? sw[bl0 * NNEI + j1] : 0.f;
    unsigned a0mi0 = ((const int*)mask_raw)[bl0 * NNEI + j0];
    unsigned a0mi1 = ((const int*)mask_raw)[bl0 * NNEI + j1c];
    unsigned a0mb0 = ((const unsigned char*)mask_raw)[bl0 * NNEI + j0];
    unsigned a0mb1 = ((const unsigned char*)mask_raw)[bl0 * NNEI + j1c];

    // ---- atom0 gg rows + qW fragments ----
    const float4* gb0 = (const float4*)(gg1 + (size_t)bl0 * NNEI * NI);
    const float4* gb1 = (const float4*)(gg1 + (size_t)bl1 * NNEI * NI);
    float4 rgA[8], rgB[8];
    load_rows(gb0, w, q, c, rgA, rgB);

    const float4* qwb0 = (const float4*)(qW_all + (size_t)bl0 * NCOL);
    float4 qwA[NH], qwB[NH];
    #pragma unroll
    for (int h = 0; h < NH; ++h) {
        qwA[h] = qwb0[h * 32 + c];
        qwB[h] = qwb0[h * 32 + c + 16];
    }

    // ================= atom 0 =================
    phase1_logits(rgA, rgB, qwA, qwB, s_sm, w, q, c);
    __syncthreads();
    const int is32 = s_is_i32;
    {
        bool m0 = is32 ? (a0mi0 != 0u) : (a0mb0 != 0u);
        bool m1 = (j1 < NNEI) && (is32 ? (a0mi1 != 0u) : (a0mb1 != 0u));
        softmax_inplace(s_sm, w, lane, m0, m1, sw0_0, sw1_0);
    }
    __syncthreads();
    phase2_partial(rgA, rgB, s_sm, s_part2, w, q, c);

    // ---- early-issue atom1 state (rg regs free after phase2) ----
    load_rows(gb1, w, q, c, rgA, rgB);
    const float4* qwb1 = (const float4*)(qW_all + (size_t)bl1 * NCOL);
    #pragma unroll
    for (int h = 0; h < NH; ++h) {
        qwA[h] = qwb1[h * 32 + c];
        qwB[h] = qwb1[h * 32 + c + 16];
    }
    bool a1m0 = load_mask(mask_raw, is32, bl1 * NNEI + j0);
    bool a1m1 = (j1 < NNEI) && load_mask(mask_raw, is32, bl1 * NNEI + j1c);
    float sw0_1 = sw[bl1 * NNEI + j0];
    float sw1_1 = (j1 < NNEI) ? sw[bl1 * NNEI + j1] : 0.f;

    __syncthreads();
    fold_t(s_part2, s_t4[0], tid);
    __syncthreads();

    // ================= atom 1 =================
    phase1_logits(rgA, rgB, qwA, qwB, s_sm, w, q, c);
    __syncthreads();
    softmax_inplace(s_sm, w, lane, a1m0, a1m1, sw0_1, sw1_1);
    __syncthreads();
    phase2_partial(rgA, rgB, s_sm, s_part2, w, q, c);
    __syncthreads();
    fold_t(s_part2, s_t4[1], tid);
    __syncthreads();

    // ---- shared epilogue: out[a] = t[a] @ P2 + bh, P2 read once ----
    {
        const int io4 = tid & 31, g = tid >> 5;       // g in 0..7
        float4 o0 = {0.f, 0.f, 0.f, 0.f};
        float4 o1 = {0.f, 0.f, 0.f, 0.f};
        const float4* P2_4 = (const float4*)P2;       // [512][32] float4
        const float* t0f = (const float*)&s_t4[0][0][0];
        const float* t1f = (const float*)&s_t4[1][0][0];
        #pragma unroll 8
        for (int it = 0; it < 64; ++it) {
            int kk = it * 8 + g;
            float4 p = P2_4[kk * 32 + io4];
            float tv0 = t0f[kk];
            float tv1 = t1f[kk];
            o0.x += tv0 * p.x; o0.y += tv0 * p.y; o0.z += tv0 * p.z; o0.w += tv0 * p.w;
            o1.x += tv1 * p.x; o1.y += tv1 * p.y; o1.z += tv1 * p.z; o1.w += tv1 * p.w;
        }
        float4* s_pp = &s_part2[0][0][0];
        s_pp[g * 33 + io4]       = o0;
        s_pp[264 + g * 33 + io4] = o1;                 // 264 = 8*33
    }
    __syncthreads();
    if (tid < 64) {
        int a = tid >> 5, io4 = tid & 31;
        const float4* s_pp = &s_part2[0][0][0];
        float4 r = {0.f, 0.f, 0.f, 0.f};
        #pragma unroll
        for (int g = 0; g < 8; ++g) {
            float4 v = s_pp[a * 264 + g * 33 + io4];
            r.x += v.x; r.y += v.y; r.z += v.z; r.w += v.w;
        }
        float4 b = ((const float4*)bh)[io4];
        r.x += b.x; r.y += b.y; r.z += b.z; r.w += b.w;
        ((float4*)out)[(size_t)(bl0 + a) * 32 + io4] = r;
    }
}

// ---------- fallback: single fused kernel (round-2 structure, M2/P2 layouts) ----------
__global__ __launch_bounds__(256, 2)
void fused_fallback(const float* __restrict__ g1, const float* __restrict__ gg1,
                    const void* __restrict__ mask_raw, const float* __restrict__ sw,
                    const float* __restrict__ M2, const float* __restrict__ P2,
                    const float* __restrict__ bh, float* __restrict__ out)
{
    __shared__ float s_gg[NNEI * 129];
    __shared__ float s_qW[NH][NI];
    __shared__ float s_attn[NH][NNEI];
    __shared__ float s_t[NH][NI];
    __shared__ float s_part[2][NI];
    __shared__ int   s_is_i32;

    const int tid = threadIdx.x;
    const int bl  = blockIdx.x;

    if (tid < 64) {
        unsigned v = ((const unsigned*)mask_raw)[tid];
        unsigned long long b = __ballot(v <= 1u);
        if (tid == 0) s_is_i32 = (b == 0xFFFFFFFFFFFFFFFFull) ? 1 : 0;
    }
    {
        const float4* gsrc = (const float4*)(gg1 + (size_t)bl * NNEI * NI);
        #pragma unroll
        for (int p = 0; p < 15; ++p) {
            int u = tid + p * 256;
            int r = u >> 5, c4 = u & 31;
            float4 v = gsrc[u];
            float* dst = &s_gg[r * 129 + c4 * 4];
            dst[0] = v.x; dst[1] = v.y; dst[2] = v.z; dst[3] = v.w;
        }
    }
    {
        const float* g1r = g1 + bl * NI;
        #pragma unroll
        for (int p = 0; p < 2; ++p) {
            int o = tid + p * 256;
            int i = o & (NI - 1);
            int h = o >> 7;
            const float* Mp = M2 + h * NI + i;
            float acc = 0.f;
            #pragma unroll 8
            for (int i2 = 0; i2 < NI; ++i2) acc += g1r[i2] * Mp[i2 * NCOL];
            s_qW[h][i] = acc;
        }
    }
    __syncthreads();
    {
        const int lane = tid & 63, h = tid >> 6;
        const int j0 = lane, j1 = lane + 64;
        const int j1c = (j1 < NNEI) ? j1 : 0;
        const float* row0 = &s_gg[j0 * 129];
        const float* row1 = &s_gg[j1c * 129];
        float dot0 = 0.f, dot1 = 0.f;
        #pragma unroll 8
        for (int i = 0; i < NI; ++i) {
            float w = s_qW[h][i];
            dot0 += row0[i] * w;
            dot1 += row1[i] * w;
        }
        bool m0 = load_mask(mask_raw, s_is_i32, bl * NNEI + j0);
        bool m1 = (j1 < NNEI) && load_mask(mask_raw, s_is_i32, bl * NNEI + j1c);
        float v0 = m0 ? dot0 : -INFINITY;
        float v1 = m1 ? dot1 : -INFINITY;
        float mx = fmaxf(v0, v1);
        #pragma unroll
        for (int off = 32; off; off >>= 1) mx = fmaxf(mx, __shfl_xor(mx, off));
        float e0 = 0.f, e1 = 0.f;
        if (mx != -INFINITY) {
            e0 = m0 ? __expf(v0 - mx) : 0.f;
            e1 = m1 ? __expf(v1 - mx) : 0.f;
        }
        float s = e0 + e1;
        #pragma unroll
        for (int off = 32; off; off >>= 1) s += __shfl_xor(s, off);
        float inv = (s > 0.f) ? (1.f / s) : 0.f;
        s_attn[h][j0] = e0 * inv * sw[bl * NNEI + j0];
        if (j1 < NNEI) s_attn[h][j1] = e1 * inv * sw[bl * NNEI + j1];
    }
    __syncthreads();
    #pragma unroll
    for (int p = 0; p < 2; ++p) {
        int o = tid + p * 256;
        int i = o & (NI - 1);
        int h = o >> 7;
        float acc = 0.f;
        #pragma unroll 8
        for (int j = 0; j < NNEI; ++j) acc += s_attn[h][j] * s_gg[j * 129 + i];
        s_t[h][i] = acc;
    }
    __syncthreads();
    {
        int io = tid & (NI - 1);
        int half = tid >> 7;
        float acc = 0.f;
        #pragma unroll 2
        for (int h = half * 2; h < half * 2 + 2; ++h) {
            const float* Pp = P2 + h * NI * NI + io;
            #pragma unroll 8
            for (int i = 0; i < NI; ++i) acc += s_t[h][i] * Pp[i * NI];
        }
        s_part[half][io] = acc;
    }
    __syncthreads();
    if (tid < NI)
        out[bl * NI + tid] = s_part[0][tid] + s_part[1][tid] + bh[tid];
}

extern "C" void kernel_launch(void* const* d_in, const int* in_sizes, int n_in,
                              void* d_out, int out_size, void* d_ws, size_t ws_size,
                              hipStream_t stream) {
    const float* g1   = (const float*)d_in[0];
    const float* gg1  = (const float*)d_in[1];
    const void*  mask = d_in[2];
    const float* sw   = (const float*)d_in[3];
    const float* Wq   = (const float*)d_in[4];
    const float* Wkv  = (const float*)d_in[5];
    const float* Wh   = (const float*)d_in[6];
    const float* bh   = (const float*)d_in[7];
    float* out = (float*)d_out;

    const int nbl = in_sizes[0] / NI;                 // nb*nloc = 2048
    const size_t nM = (size_t)NI * NCOL;              // 65536
    const size_t nP = (size_t)NCOL * NI;              // 65536
    const size_t nQ = (size_t)nbl * NCOL;             // 1048576

    float* M2 = (float*)d_ws;
    float* P2 = M2 + nM;

    const bool main_path = (ws_size >= (nM + nP + nQ) * sizeof(float)) &&
                           (nbl == 2048);

    if (main_path) {
        float* qW = P2 + nP;
        precompute_M2<<<256, 256, 0, stream>>>(Wq, Wkv, M2);
        gemm1_p2<<<512, 256, 0, stream>>>(g1, M2, Wkv, Wh, qW, P2);
        atten2_kernel<<<nbl / 2, 256, 0, stream>>>(gg1, qW, mask, sw, P2, bh, out);
    } else {
        precompute_MP<<<512, 256, 0, stream>>>(Wq, Wkv, Wh, M2, P2);
        fused_fallback<<<nbl, 256, 0, stream>>>(g1, gg1, mask, sw, M2, P2, bh, out);
    }
}